// Round 2
// baseline (218.365 us; speedup 1.0000x reference)
//
#include <hip/hip_runtime.h>
#include <hip/hip_bf16.h>

// LinearAttention_MLP on MI355X — round 2.
// Math: k-softmax over size-1 axis == 1, so s = sum_d softmax(q)_d*SCALE = 0.125
// exactly -> out = 0.125*v. Further fold: y = (0.125*x@Wv^T)@Wo^T
//                                          = x @ Weff^T,  Weff = 0.125*Wo@Wv.
// Pipeline:
//   x_bf   = bf16(x)
//   wo_bf  = bf16(Wo); wvT_bf = bf16(Wv^T)            (small)
//   Weff   = 0.125 * Wo @ Wv      (1024x1024, K=512)  (small MFMA GEMM)
//   y_bf   = bf16(x @ Weff^T + b) (main GEMM, M=16384,N=1024,K=1024)
//   out    = y / max(||y||,eps) * g * 32   (fp32 out)

typedef __attribute__((ext_vector_type(8))) short bf16x8;   // 8 bf16 = 4 VGPRs
typedef __attribute__((ext_vector_type(4))) float f32x4;

#define BLK 128
#define BK  32

// ---------------- cast fp32 -> bf16, 8 elems/thread ----------------
struct alignas(16) bfvec8 { __hip_bfloat16 h[8]; };

__global__ __launch_bounds__(256)
void cast_bf16(const float* __restrict__ in, bfvec8* __restrict__ out, int n8) {
    int i = blockIdx.x * blockDim.x + threadIdx.x;
    if (i >= n8) return;
    const float4* p = (const float4*)in + (size_t)i * 2;
    float4 a = p[0];
    float4 b = p[1];
    bfvec8 o;
    o.h[0] = __float2bfloat16(a.x); o.h[1] = __float2bfloat16(a.y);
    o.h[2] = __float2bfloat16(a.z); o.h[3] = __float2bfloat16(a.w);
    o.h[4] = __float2bfloat16(b.x); o.h[5] = __float2bfloat16(b.y);
    o.h[6] = __float2bfloat16(b.z); o.h[7] = __float2bfloat16(b.w);
    out[i] = o;
}

// ---------------- transpose + cast: Wv (512,1024) fp32 -> WvT (1024,512) bf16 ----------------
__global__ __launch_bounds__(256)
void transpose_cast(const float* __restrict__ in, __hip_bfloat16* __restrict__ out,
                    int rows, int cols) {  // in: rows x cols; out: cols x rows
    __shared__ float tile[32][33];
    const int c = threadIdx.x & 31;        // 0..31
    const int r8 = threadIdx.x >> 5;       // 0..7
    const int c0 = blockIdx.x * 32;        // col tile origin
    const int r0 = blockIdx.y * 32;        // row tile origin
#pragma unroll
    for (int i = 0; i < 4; ++i) {
        int r = r8 + i * 8;
        tile[r][c] = in[(size_t)(r0 + r) * cols + c0 + c];
    }
    __syncthreads();
#pragma unroll
    for (int i = 0; i < 4; ++i) {
        int r = r8 + i * 8;                // output row within tile (= input col)
        out[(size_t)(c0 + r) * rows + r0 + c] = __float2bfloat16(tile[c][r]);
    }
}

// ---------------- m97-style bf16 GEMM, B given transposed (N,K) ----------------
// C = alpha * A @ Bt^T + bias, A: MxK, Bt: NxK, C: MxN.
// 256 threads = 4 waves in 2x2; each wave computes 64x64 via 4x4 frags of 16x16x32.
template<bool WRITE_BF16>
__global__ __launch_bounds__(256)
void gemm_bt(const __hip_bfloat16* __restrict__ A,
             const __hip_bfloat16* __restrict__ Bt,
             void* __restrict__ Cout,
             const float* __restrict__ bias,
             int M, int N, int K, float alpha)
{
    __shared__ __align__(16) __hip_bfloat16 As[BLK * BK];  // [m][k] row-major, 8 KB
    __shared__ __align__(16) __hip_bfloat16 Bs[BLK * BK];  // [n][k] row-major, 8 KB

    const int tid  = threadIdx.x;
    const int lane = tid & 63;
    const int wave = tid >> 6;     // 0..3
    const int wm   = wave >> 1;    // 0..1  (row half)
    const int wn   = wave & 1;     // 0..1  (col half)
    const int quad = lane >> 4;    // 0..3
    const int tr   = lane & 15;    // 0..15

    const int m0 = blockIdx.y * BLK;
    const int n0 = blockIdx.x * BLK;

    f32x4 acc[4][4];
#pragma unroll
    for (int i = 0; i < 4; ++i)
#pragma unroll
        for (int j = 0; j < 4; ++j)
            acc[i][j] = (f32x4){0.f, 0.f, 0.f, 0.f};

    for (int kt = 0; kt < K; kt += BK) {
        // Stage 128x32 bf16 tiles (8 KB each) via async global->LDS, 16 B/lane.
#pragma unroll
        for (int i = 0; i < 2; ++i) {
            int L  = i * 256 + wave * 64 + lane;   // 0..511
            int r  = L >> 2;                       // tile row 0..127
            int c8 = (L & 3) << 3;                 // k-offset {0,8,16,24}
            const __hip_bfloat16* ga = A  + (size_t)(m0 + r) * K + kt + c8;
            const __hip_bfloat16* gb = Bt + (size_t)(n0 + r) * K + kt + c8;
            __builtin_amdgcn_global_load_lds(
                (const __attribute__((address_space(1))) void*)ga,
                (__attribute__((address_space(3))) void*)(As + (size_t)L * 8), 16, 0, 0);
            __builtin_amdgcn_global_load_lds(
                (const __attribute__((address_space(1))) void*)gb,
                (__attribute__((address_space(3))) void*)(Bs + (size_t)L * 8), 16, 0, 0);
        }
        __syncthreads();

        bf16x8 af[4], bf[4];
#pragma unroll
        for (int mi = 0; mi < 4; ++mi)
            af[mi] = *(const bf16x8*)(As + ((wm * 64 + mi * 16 + tr) * BK + quad * 8));
#pragma unroll
        for (int ni = 0; ni < 4; ++ni)
            bf[ni] = *(const bf16x8*)(Bs + ((wn * 64 + ni * 16 + tr) * BK + quad * 8));

#pragma unroll
        for (int mi = 0; mi < 4; ++mi)
#pragma unroll
            for (int ni = 0; ni < 4; ++ni)
                acc[mi][ni] = __builtin_amdgcn_mfma_f32_16x16x32_bf16(
                    af[mi], bf[ni], acc[mi][ni], 0, 0, 0);

        __syncthreads();
    }

    // Epilogue. C/D layout: col = lane&15, row = quad*4 + reg.
#pragma unroll
    for (int mi = 0; mi < 4; ++mi) {
#pragma unroll
        for (int ni = 0; ni < 4; ++ni) {
            const int col = n0 + wn * 64 + ni * 16 + tr;
            const float b = (bias != nullptr) ? bias[col] : 0.f;
#pragma unroll
            for (int r = 0; r < 4; ++r) {
                const int row = m0 + wm * 64 + mi * 16 + quad * 4 + r;
                float val = acc[mi][ni][r] * alpha + b;
                if (WRITE_BF16)
                    ((__hip_bfloat16*)Cout)[(size_t)row * N + col] = __float2bfloat16(val);
                else
                    ((float*)Cout)[(size_t)row * N + col] = val;
            }
        }
    }
}

// ---------------- per-row norm: out = y / max(||y||,eps) * g * 32, y bf16 -> out fp32 ----------------
__global__ __launch_bounds__(256)
void rmsnorm_rows(const __hip_bfloat16* __restrict__ y, const float* __restrict__ g,
                  float* __restrict__ out) {
    const int row = blockIdx.x;
    const int tid = threadIdx.x;
    const ushort4 u = *(const ushort4*)(y + (size_t)row * 1024 + tid * 4);
    float4 v;
    v.x = __bfloat162float(*(const __hip_bfloat16*)&u.x);
    v.y = __bfloat162float(*(const __hip_bfloat16*)&u.y);
    v.z = __bfloat162float(*(const __hip_bfloat16*)&u.z);
    v.w = __bfloat162float(*(const __hip_bfloat16*)&u.w);
    float ss = v.x * v.x + v.y * v.y + v.z * v.z + v.w * v.w;
#pragma unroll
    for (int off = 32; off > 0; off >>= 1)
        ss += __shfl_down(ss, off, 64);
    __shared__ float wsum[4];
    if ((tid & 63) == 0) wsum[tid >> 6] = ss;
    __syncthreads();
    const float total = wsum[0] + wsum[1] + wsum[2] + wsum[3];
    const float sc = 32.0f / fmaxf(sqrtf(total), 1e-12f);
    const float4 gv = *(const float4*)(g + tid * 4);
    float4 o;
    o.x = v.x * sc * gv.x; o.y = v.y * sc * gv.y;
    o.z = v.z * sc * gv.z; o.w = v.w * sc * gv.w;
    *(float4*)(out + (size_t)row * 1024 + tid * 4) = o;
}

extern "C" void kernel_launch(void* const* d_in, const int* in_sizes, int n_in,
                              void* d_out, int out_size, void* d_ws, size_t ws_size,
                              hipStream_t stream) {
    const float* x     = (const float*)d_in[0];   // (16384, 1024)
    const float* w_qkv = (const float*)d_in[1];   // (1536, 1024)
    const float* w_out = (const float*)d_in[2];   // (1024, 512)
    const float* b_out = (const float*)d_in[3];   // (1024,)
    const float* g     = (const float*)d_in[4];   // (1, 1024)

    const int B = 16384, D = 1024, H = 512;
    const float* wv = w_qkv + (size_t)2 * H * D;  // v-rows of qkv weight: (512, 1024)

    char* ws = (char*)d_ws;
    size_t off = 0;
    __hip_bfloat16* x_bf    = (__hip_bfloat16*)(ws + off); off += (size_t)B * D * 2;  // 32 MB
    __hip_bfloat16* wo_bf   = (__hip_bfloat16*)(ws + off); off += (size_t)D * H * 2;  // 1 MB
    __hip_bfloat16* wvT_bf  = (__hip_bfloat16*)(ws + off); off += (size_t)D * H * 2;  // 1 MB
    __hip_bfloat16* weff_bf = (__hip_bfloat16*)(ws + off); off += (size_t)D * D * 2;  // 2 MB
    __hip_bfloat16* y_bf    = (__hip_bfloat16*)(ws + off); off += (size_t)B * D * 2;  // 32 MB

    // 1) casts
    cast_bf16<<<(B * D / 8) / 256, 256, 0, stream>>>(x, (bfvec8*)x_bf, B * D / 8);
    cast_bf16<<<(D * H / 8) / 256, 256, 0, stream>>>(w_out, (bfvec8*)wo_bf, D * H / 8);
    // WvT (1024,512) <- Wv (512,1024)
    transpose_cast<<<dim3(D / 32, H / 32), 256, 0, stream>>>(wv, wvT_bf, H, D);

    // 2) Weff = 0.125 * Wo @ Wv  (M=D, N=D, K=H), bf16 out
    gemm_bt<true><<<dim3(D / BLK, D / BLK), 256, 0, stream>>>(
        wo_bf, wvT_bf, (void*)weff_bf, nullptr, D, D, H, 0.125f);

    // 3) y = x @ Weff^T + b_out  (M=B, N=D, K=D) -> bf16
    gemm_bt<true><<<dim3(D / BLK, B / BLK), 256, 0, stream>>>(
        x_bf, weff_bf, (void*)y_bf, b_out, B, D, D, 1.0f);

    // 4) norm: out = y/||y|| * g * 32
    rmsnorm_rows<<<B, 256, 0, stream>>>(y_bf, g, (float*)d_out);
}

// Round 3
// 203.166 us; speedup vs baseline: 1.0748x; 1.0748x over previous
//
#include <hip/hip_runtime.h>
#include <hip/hip_bf16.h>

// LinearAttention_MLP on MI355X — round 3.
// Math: k-softmax over size-1 axis == 1 -> s = 0.125 exactly -> out = 0.125*v.
// Fold: y = x @ Weff^T, Weff = 0.125*Wo@Wv (1024x1024).
// Pipeline (4 launches):
//   cast_x     : x fp32 -> bf16                                  (96 MB traffic)
//   weff_fused : Weff = bf16(0.125*Wo@Wv) from fp32 inputs       (tiny)
//   main_gemm  : y_bf = bf16(x@Weff^T + b)  M=16384,N=1024,K=1024
//                XCD-swizzled grid (A fetched once per strip), BK=64,
//                XOR-swizzled LDS chunks (conflict-free frag reads)
//   rmsnorm2   : out = y/max(||y||,eps)*g*32  (fp32)

typedef __attribute__((ext_vector_type(8))) short bf16x8;
typedef __attribute__((ext_vector_type(4))) float f32x4;

// ---------------- cast fp32 -> bf16, 8 elems/thread ----------------
struct alignas(16) bfvec8 { __hip_bfloat16 h[8]; };

__device__ __forceinline__ bfvec8 pack8(float4 a, float4 b) {
    bfvec8 o;
    o.h[0] = __float2bfloat16(a.x); o.h[1] = __float2bfloat16(a.y);
    o.h[2] = __float2bfloat16(a.z); o.h[3] = __float2bfloat16(a.w);
    o.h[4] = __float2bfloat16(b.x); o.h[5] = __float2bfloat16(b.y);
    o.h[6] = __float2bfloat16(b.z); o.h[7] = __float2bfloat16(b.w);
    return o;
}

__global__ __launch_bounds__(256)
void cast_bf16(const float* __restrict__ in, bfvec8* __restrict__ out, int n8) {
    int i = blockIdx.x * blockDim.x + threadIdx.x;
    if (i >= n8) return;
    const float4* p = (const float4*)in + (size_t)i * 2;
    out[i] = pack8(p[0], p[1]);
}

// ---------------- weff_fused: Weff = 0.125 * Wo @ Wv, fp32 in, bf16 out ----------------
// Wo: (1024,512) row-major (K-major). Wv: (512,1024) row-major (needs transpose).
// M=N=1024, K=512, BLK=128, BK=32, grid 8x8.
__global__ __launch_bounds__(256)
void weff_fused(const float* __restrict__ Wo, const float* __restrict__ Wv,
                __hip_bfloat16* __restrict__ Weff) {
    __shared__ __align__(16) __hip_bfloat16 As[128 * 32];
    __shared__ __align__(16) __hip_bfloat16 Bs[128 * 32];
    __shared__ __align__(16) float Bf[32 * 132];   // fp32 staging for transpose, padded

    const int tid  = threadIdx.x;
    const int lane = tid & 63;
    const int wave = tid >> 6;
    const int wm   = wave >> 1;
    const int wn   = wave & 1;
    const int quad = lane >> 4;
    const int tr   = lane & 15;
    const int m0   = blockIdx.y * 128;
    const int n0   = blockIdx.x * 128;

    f32x4 acc[4][4];
#pragma unroll
    for (int i = 0; i < 4; ++i)
#pragma unroll
        for (int j = 0; j < 4; ++j)
            acc[i][j] = (f32x4){0.f, 0.f, 0.f, 0.f};

    for (int kt = 0; kt < 512; kt += 32) {
        // A tile: Wo[m0+r][kt + c8..c8+8), cvt -> As[r][c8..]
#pragma unroll
        for (int i = 0; i < 2; ++i) {
            int L = i * 256 + tid;           // 0..511
            int r = L >> 2, c8 = (L & 3) << 3;
            const float* s = Wo + (size_t)(m0 + r) * 512 + kt + c8;
            float4 a = *(const float4*)s, b = *(const float4*)(s + 4);
            *(bfvec8*)(As + r * 32 + c8) = pack8(a, b);
        }
        // B fp32 tile (coalesced): Bf[kr][c] = Wv[kt+kr][n0+c]
#pragma unroll
        for (int i = 0; i < 2; ++i) {
            int L = i * 256 + tid;
            int kr = L >> 4, c8 = (L & 15) << 3;
            const float* s = Wv + (size_t)(kt + kr) * 1024 + n0 + c8;
            float4 a = *(const float4*)s, b = *(const float4*)(s + 4);
            *(float4*)(Bf + kr * 132 + c8)     = a;
            *(float4*)(Bf + kr * 132 + c8 + 4) = b;
        }
        __syncthreads();
        // transpose + cvt: Bs[n][k8..k8+8) = Bf[k8+j][n]
#pragma unroll
        for (int i = 0; i < 2; ++i) {
            int L = i * 256 + tid;
            int n = L >> 2, k8 = (L & 3) << 3;
            float4 a, b;
            a.x = Bf[(k8 + 0) * 132 + n]; a.y = Bf[(k8 + 1) * 132 + n];
            a.z = Bf[(k8 + 2) * 132 + n]; a.w = Bf[(k8 + 3) * 132 + n];
            b.x = Bf[(k8 + 4) * 132 + n]; b.y = Bf[(k8 + 5) * 132 + n];
            b.z = Bf[(k8 + 6) * 132 + n]; b.w = Bf[(k8 + 7) * 132 + n];
            *(bfvec8*)(Bs + n * 32 + k8) = pack8(a, b);
        }
        __syncthreads();

        bf16x8 af[4], bf[4];
#pragma unroll
        for (int mi = 0; mi < 4; ++mi)
            af[mi] = *(const bf16x8*)(As + ((wm * 64 + mi * 16 + tr) * 32 + quad * 8));
#pragma unroll
        for (int ni = 0; ni < 4; ++ni)
            bf[ni] = *(const bf16x8*)(Bs + ((wn * 64 + ni * 16 + tr) * 32 + quad * 8));
#pragma unroll
        for (int mi = 0; mi < 4; ++mi)
#pragma unroll
            for (int ni = 0; ni < 4; ++ni)
                acc[mi][ni] = __builtin_amdgcn_mfma_f32_16x16x32_bf16(
                    af[mi], bf[ni], acc[mi][ni], 0, 0, 0);
        __syncthreads();
    }

#pragma unroll
    for (int mi = 0; mi < 4; ++mi)
#pragma unroll
        for (int ni = 0; ni < 4; ++ni) {
            const int col = n0 + wn * 64 + ni * 16 + tr;
#pragma unroll
            for (int r = 0; r < 4; ++r) {
                const int row = m0 + wm * 64 + mi * 16 + quad * 4 + r;
                Weff[(size_t)row * 1024 + col] =
                    __float2bfloat16(acc[mi][ni][r] * 0.125f);
            }
        }
}

// ---------------- main GEMM: y = x @ Weff^T + b, bf16 out ----------------
// M=16384, N=1024, K=1024, BLK=128, BK=64. 1D grid of 1024 blocks.
// XCD swizzle: all 8 n-tiles of an m-strip on one XCD -> A fetched once.
// LDS chunk XOR swizzle: chunk c at row r holds global k-chunk (c ^ (r&7)).
__global__ __launch_bounds__(256)
void main_gemm(const __hip_bfloat16* __restrict__ A,
               const __hip_bfloat16* __restrict__ Bt,
               const float* __restrict__ bias,
               __hip_bfloat16* __restrict__ Y) {
    __shared__ __align__(16) __hip_bfloat16 As[128 * 64];
    __shared__ __align__(16) __hip_bfloat16 Bs[128 * 64];

    const int tid  = threadIdx.x;
    const int lane = tid & 63;
    const int wave = tid >> 6;
    const int wm   = wave >> 1;
    const int wn   = wave & 1;
    const int quad = lane >> 4;
    const int tr   = lane & 15;

    // XCD-aware tile mapping (assumes round-robin blockIdx%8 -> XCD; worst case neutral)
    const int b   = blockIdx.x;
    const int xcd = b & 7;
    const int t   = b >> 3;
    const int nt  = t & 7;                 // 8 n-tiles
    const int mt  = (t >> 3) * 8 + xcd;    // 128 m-tiles
    const int m0  = mt * 128;
    const int n0  = nt * 128;

    f32x4 acc[4][4];
#pragma unroll
    for (int i = 0; i < 4; ++i)
#pragma unroll
        for (int j = 0; j < 4; ++j)
            acc[i][j] = (f32x4){0.f, 0.f, 0.f, 0.f};

    for (int kt = 0; kt < 1024; kt += 64) {
        // Stage 128x64 bf16 tiles (16 KB each). Slot L holds row r = L>>3,
        // LDS chunk c = L&7 whose GLOBAL k-chunk is c ^ (r&7) (XOR swizzle).
        // Lane-linear LDS dest (L*16 B); global reads stay within the same
        // 128-B line per 8-lane group -> fully coalesced.
#pragma unroll
        for (int i = 0; i < 4; ++i) {
            int L = i * 256 + tid;                 // 0..1023
            int r = L >> 3;
            int c = L & 7;
            int kg = (c ^ (r & 7)) << 3;           // swizzled global k-offset
            const __hip_bfloat16* ga = A  + (size_t)(m0 + r) * 1024 + kt + kg;
            const __hip_bfloat16* gb = Bt + (size_t)(n0 + r) * 1024 + kt + kg;
            __builtin_amdgcn_global_load_lds(
                (const __attribute__((address_space(1))) void*)ga,
                (__attribute__((address_space(3))) void*)(As + (size_t)L * 8), 16, 0, 0);
            __builtin_amdgcn_global_load_lds(
                (const __attribute__((address_space(1))) void*)gb,
                (__attribute__((address_space(3))) void*)(Bs + (size_t)L * 8), 16, 0, 0);
        }
        __syncthreads();

#pragma unroll
        for (int ko = 0; ko < 2; ++ko) {
            bf16x8 af[4], bf[4];
#pragma unroll
            for (int mi = 0; mi < 4; ++mi) {
                int r = wm * 64 + mi * 16 + tr;
                int c = (ko * 4 + quad) ^ (r & 7);   // un-swizzle
                af[mi] = *(const bf16x8*)(As + (r * 8 + c) * 8);
            }
#pragma unroll
            for (int ni = 0; ni < 4; ++ni) {
                int r = wn * 64 + ni * 16 + tr;
                int c = (ko * 4 + quad) ^ (r & 7);
                bf[ni] = *(const bf16x8*)(Bs + (r * 8 + c) * 8);
            }
#pragma unroll
            for (int mi = 0; mi < 4; ++mi)
#pragma unroll
                for (int ni = 0; ni < 4; ++ni)
                    acc[mi][ni] = __builtin_amdgcn_mfma_f32_16x16x32_bf16(
                        af[mi], bf[ni], acc[mi][ni], 0, 0, 0);
        }
        __syncthreads();
    }

    // Epilogue: C/D layout col = lane&15, row = quad*4 + reg.
#pragma unroll
    for (int mi = 0; mi < 4; ++mi)
#pragma unroll
        for (int ni = 0; ni < 4; ++ni) {
            const int col = n0 + wn * 64 + ni * 16 + tr;
            const float bv = bias[col];
#pragma unroll
            for (int r = 0; r < 4; ++r) {
                const int row = m0 + wm * 64 + mi * 16 + quad * 4 + r;
                Y[(size_t)row * 1024 + col] = __float2bfloat16(acc[mi][ni][r] + bv);
            }
        }
}

// ---------------- norm: out = y / max(||y||,eps) * g * 32, 2 rows/block ----------------
__global__ __launch_bounds__(256)
void rmsnorm2(const __hip_bfloat16* __restrict__ y, const float* __restrict__ g,
              float* __restrict__ out) {
    const int wave = threadIdx.x >> 6;     // 0..3
    const int sub  = wave >> 1;            // which of 2 rows
    const int t    = threadIdx.x & 127;    // 0..127 within row
    const int row  = blockIdx.x * 2 + sub;
    const size_t base = (size_t)row * 1024 + t * 8;

    union { uint4 u; ushort s[8]; } U;
    U.u = *(const uint4*)(y + base);
    float v[8];
#pragma unroll
    for (int j = 0; j < 8; ++j)
        v[j] = __bfloat162float(*(const __hip_bfloat16*)&U.s[j]);

    float ss = 0.f;
#pragma unroll
    for (int j = 0; j < 8; ++j) ss += v[j] * v[j];
#pragma unroll
    for (int off = 32; off > 0; off >>= 1)
        ss += __shfl_down(ss, off, 64);

    __shared__ float wsum[4];
    if ((threadIdx.x & 63) == 0) wsum[wave] = ss;
    __syncthreads();
    const float total = wsum[sub * 2] + wsum[sub * 2 + 1];
    const float sc = 32.0f / fmaxf(sqrtf(total), 1e-12f);

    const float4 g0 = *(const float4*)(g + t * 8);
    const float4 g1 = *(const float4*)(g + t * 8 + 4);
    float4 o0, o1;
    o0.x = v[0] * sc * g0.x; o0.y = v[1] * sc * g0.y;
    o0.z = v[2] * sc * g0.z; o0.w = v[3] * sc * g0.w;
    o1.x = v[4] * sc * g1.x; o1.y = v[5] * sc * g1.y;
    o1.z = v[6] * sc * g1.z; o1.w = v[7] * sc * g1.w;
    *(float4*)(out + base)     = o0;
    *(float4*)(out + base + 4) = o1;
}

extern "C" void kernel_launch(void* const* d_in, const int* in_sizes, int n_in,
                              void* d_out, int out_size, void* d_ws, size_t ws_size,
                              hipStream_t stream) {
    const float* x     = (const float*)d_in[0];   // (16384, 1024)
    const float* w_qkv = (const float*)d_in[1];   // (1536, 1024)
    const float* w_out = (const float*)d_in[2];   // (1024, 512)
    const float* b_out = (const float*)d_in[3];   // (1024,)
    const float* g     = (const float*)d_in[4];   // (1, 1024)

    const int B = 16384, D = 1024, H = 512;
    const float* wv = w_qkv + (size_t)2 * H * D;  // v-rows: (512, 1024)

    char* ws = (char*)d_ws;
    size_t off = 0;
    __hip_bfloat16* x_bf    = (__hip_bfloat16*)(ws + off); off += (size_t)B * D * 2;  // 32 MB
    __hip_bfloat16* weff_bf = (__hip_bfloat16*)(ws + off); off += (size_t)D * D * 2;  // 2 MB
    __hip_bfloat16* y_bf    = (__hip_bfloat16*)(ws + off); off += (size_t)B * D * 2;  // 32 MB

    cast_bf16<<<(B * D / 8) / 256, 256, 0, stream>>>(x, (bfvec8*)x_bf, B * D / 8);
    weff_fused<<<dim3(8, 8), 256, 0, stream>>>(w_out, wv, weff_bf);
    main_gemm<<<1024, 256, 0, stream>>>(x_bf, weff_bf, b_out, y_bf);
    rmsnorm2<<<B / 2, 256, 0, stream>>>(y_bf, g, (float*)d_out);
}

// Round 5
// 192.978 us; speedup vs baseline: 1.1316x; 1.0528x over previous
//
#include <hip/hip_runtime.h>
#include <hip/hip_bf16.h>

// LinearAttention_MLP on MI355X — round 5 (round 4 + weff swizzle bugfix).
// Math: k-softmax over size-1 axis == 1 -> s = 0.125 exactly -> out = 0.125*v.
// Fold: y = x @ Weff^T, Weff = 0.125*Wo@Wv (1024x1024).
// Pipeline (3 launches):
//   weff_fused : Weff = bf16(0.125*Wo@Wv) fp32 in, 64x64 tiles, 256 blocks
//   main_gemm  : y_bf = bf16(x@Weff^T + b), A read fp32 + cvt in staging
//                (reg-prefetched one K-step ahead); XCD swizzle; XOR LDS swizzle
//   rmsnorm2   : out = y/max(||y||,eps)*g*32  (fp32)
//
// Swizzle convention (round-3 validated, round-4 bug was violating it):
//   STORE: LDS chunk c holds GLOBAL chunk c ^ s   (swizzle the global offset only)
//   READ : to get global chunk q, read LDS chunk q ^ s

typedef __attribute__((ext_vector_type(8))) short bf16x8;
typedef __attribute__((ext_vector_type(4))) float f32x4;

struct alignas(16) bfvec8 { __hip_bfloat16 h[8]; };

__device__ __forceinline__ bfvec8 pack8(float4 a, float4 b) {
    bfvec8 o;
    o.h[0] = __float2bfloat16(a.x); o.h[1] = __float2bfloat16(a.y);
    o.h[2] = __float2bfloat16(a.z); o.h[3] = __float2bfloat16(a.w);
    o.h[4] = __float2bfloat16(b.x); o.h[5] = __float2bfloat16(b.y);
    o.h[6] = __float2bfloat16(b.z); o.h[7] = __float2bfloat16(b.w);
    return o;
}

// ---------------- weff_fused: Weff = 0.125 * Wo @ Wv, fp32 in, bf16 out ----------------
// Wo: (1024,512) row-major. Wv: (512,1024) row-major (transposed in LDS).
// 64x64 tiles, BK=32, grid 16x16 = 256 blocks (all CUs busy).
__global__ __launch_bounds__(256)
void weff_fused(const float* __restrict__ Wo, const float* __restrict__ Wv,
                __hip_bfloat16* __restrict__ Weff) {
    __shared__ __align__(16) __hip_bfloat16 As[64 * 32];
    __shared__ __align__(16) __hip_bfloat16 Bs[64 * 32];
    __shared__ __align__(16) float Bf[32 * 65];   // fp32 transpose staging, stride 65

    const int tid  = threadIdx.x;
    const int lane = tid & 63;
    const int wave = tid >> 6;
    const int wm   = wave >> 1;
    const int wn   = wave & 1;
    const int quad = lane >> 4;
    const int tr   = lane & 15;
    const int m0   = blockIdx.y * 64;
    const int n0   = blockIdx.x * 64;

    f32x4 acc[2][2];
#pragma unroll
    for (int i = 0; i < 2; ++i)
#pragma unroll
        for (int j = 0; j < 2; ++j)
            acc[i][j] = (f32x4){0.f, 0.f, 0.f, 0.f};

    for (int kt = 0; kt < 512; kt += 32) {
        // A: 64x32 fp32 -> cvt -> As. LDS chunk c holds global chunk c ^ s.
        {
            int r = tid >> 2, c = tid & 3;
            int s = (r >> 1) & 3;
            int kg = (c ^ s) << 3;                 // global chunk for LDS chunk c
            const float* sp = Wo + (size_t)(m0 + r) * 512 + kt + kg;
            float4 a = *(const float4*)sp, b = *(const float4*)(sp + 4);
            *(bfvec8*)(As + r * 32 + (c << 3)) = pack8(a, b);   // un-swizzled LDS addr
        }
        // B fp32 (coalesced rows of Wv) -> Bf
        {
            int kr = tid >> 3, c8 = (tid & 7) << 3;
            const float* sp = Wv + (size_t)(kt + kr) * 1024 + n0 + c8;
            float4 a = *(const float4*)sp, b = *(const float4*)(sp + 4);
            *(float4*)(Bf + kr * 65 + c8)     = a;
            *(float4*)(Bf + kr * 65 + c8 + 4) = b;
        }
        __syncthreads();
        // transpose + cvt: LDS chunk (cc ^ s) holds global chunk cc
        {
            int n = tid >> 2, cc = tid & 3, k8 = cc << 3;
            float4 a, b;
            a.x = Bf[(k8 + 0) * 65 + n]; a.y = Bf[(k8 + 1) * 65 + n];
            a.z = Bf[(k8 + 2) * 65 + n]; a.w = Bf[(k8 + 3) * 65 + n];
            b.x = Bf[(k8 + 4) * 65 + n]; b.y = Bf[(k8 + 5) * 65 + n];
            b.z = Bf[(k8 + 6) * 65 + n]; b.w = Bf[(k8 + 7) * 65 + n];
            int cs = cc ^ ((n >> 1) & 3);
            *(bfvec8*)(Bs + n * 32 + cs * 8) = pack8(a, b);
        }
        __syncthreads();

        bf16x8 af[2], bf[2];
#pragma unroll
        for (int mi = 0; mi < 2; ++mi) {
            int r = wm * 32 + mi * 16 + tr;
            int c = quad ^ ((r >> 1) & 3);         // LDS chunk holding global chunk quad
            af[mi] = *(const bf16x8*)(As + r * 32 + c * 8);
        }
#pragma unroll
        for (int ni = 0; ni < 2; ++ni) {
            int r = wn * 32 + ni * 16 + tr;
            int c = quad ^ ((r >> 1) & 3);
            bf[ni] = *(const bf16x8*)(Bs + r * 32 + c * 8);
        }
#pragma unroll
        for (int mi = 0; mi < 2; ++mi)
#pragma unroll
            for (int ni = 0; ni < 2; ++ni)
                acc[mi][ni] = __builtin_amdgcn_mfma_f32_16x16x32_bf16(
                    af[mi], bf[ni], acc[mi][ni], 0, 0, 0);
        __syncthreads();
    }

#pragma unroll
    for (int mi = 0; mi < 2; ++mi)
#pragma unroll
        for (int ni = 0; ni < 2; ++ni) {
            const int col = n0 + wn * 32 + ni * 16 + tr;
#pragma unroll
            for (int r = 0; r < 4; ++r) {
                const int row = m0 + wm * 32 + mi * 16 + quad * 4 + r;
                Weff[(size_t)row * 1024 + col] =
                    __float2bfloat16(acc[mi][ni][r] * 0.125f);
            }
        }
}

// ---------------- main GEMM: y = x @ Weff^T + b, x fp32 (cvt fused), bf16 out ----------------
// M=16384, N=1024, K=1024, BLK=128, BK=64. 1D grid of 1024 blocks.
// A: fp32 global -> regs (prefetched one K-step ahead) -> cvt -> ds_write.
// B: global_load_lds. XOR chunk swizzle on both tiles (round-3 validated: 0 conflicts).
__global__ __launch_bounds__(256)
void main_gemm(const float* __restrict__ X,
               const __hip_bfloat16* __restrict__ Bt,
               const float* __restrict__ bias,
               __hip_bfloat16* __restrict__ Y) {
    __shared__ __align__(16) __hip_bfloat16 As[128 * 64];
    __shared__ __align__(16) __hip_bfloat16 Bs[128 * 64];

    const int tid  = threadIdx.x;
    const int lane = tid & 63;
    const int wave = tid >> 6;
    const int wm   = wave >> 1;
    const int wn   = wave & 1;
    const int quad = lane >> 4;
    const int tr   = lane & 15;

    // XCD-aware mapping: all 8 n-tiles of an m-strip on one XCD (A fetched once)
    const int b   = blockIdx.x;
    const int xcd = b & 7;
    const int t   = b >> 3;
    const int nt  = t & 7;
    const int mt  = (t >> 3) * 8 + xcd;
    const int m0  = mt * 128;
    const int n0  = nt * 128;

    // Per-slot constants for the 4 staging slots this thread owns.
    // Slot L: LDS chunk c = L&7 holds global chunk c ^ (r&7).
    int rr[4], kgg[4];
    size_t abase[4];
#pragma unroll
    for (int i = 0; i < 4; ++i) {
        int L = i * 256 + tid;            // 0..1023
        rr[i]  = L >> 3;                  // tile row 0..127
        int c  = L & 7;                   // LDS chunk
        kgg[i] = (c ^ (rr[i] & 7)) << 3;  // swizzled global k-offset (elements)
        abase[i] = (size_t)(m0 + rr[i]) * 1024 + kgg[i];
    }

    f32x4 acc[4][4];
#pragma unroll
    for (int i = 0; i < 4; ++i)
#pragma unroll
        for (int j = 0; j < 4; ++j)
            acc[i][j] = (f32x4){0.f, 0.f, 0.f, 0.f};

    // Prologue: prefetch A regs for kt=0
    float4 pa[4], pb[4];
#pragma unroll
    for (int i = 0; i < 4; ++i) {
        const float* s = X + abase[i];
        pa[i] = *(const float4*)s;
        pb[i] = *(const float4*)(s + 4);
    }

    for (int kt = 0; kt < 1024; kt += 64) {
        // Stage B (async direct-to-LDS) and A (regs -> cvt -> LDS)
#pragma unroll
        for (int i = 0; i < 4; ++i) {
            int L = i * 256 + tid;
            const __hip_bfloat16* gb = Bt + (size_t)(n0 + rr[i]) * 1024 + kt + kgg[i];
            __builtin_amdgcn_global_load_lds(
                (const __attribute__((address_space(1))) void*)gb,
                (__attribute__((address_space(3))) void*)(Bs + (size_t)L * 8), 16, 0, 0);
        }
#pragma unroll
        for (int i = 0; i < 4; ++i) {
            int L = i * 256 + tid;
            *(bfvec8*)(As + (size_t)L * 8) = pack8(pa[i], pb[i]);
        }
        __syncthreads();

        // Prefetch next K-step's A while MFMAs run
        if (kt + 64 < 1024) {
#pragma unroll
            for (int i = 0; i < 4; ++i) {
                const float* s = X + abase[i] + kt + 64;
                pa[i] = *(const float4*)s;
                pb[i] = *(const float4*)(s + 4);
            }
        }

#pragma unroll
        for (int ko = 0; ko < 2; ++ko) {
            bf16x8 af[4], bf[4];
#pragma unroll
            for (int mi = 0; mi < 4; ++mi) {
                int r = wm * 64 + mi * 16 + tr;
                int c = (ko * 4 + quad) ^ (r & 7);
                af[mi] = *(const bf16x8*)(As + (r * 8 + c) * 8);
            }
#pragma unroll
            for (int ni = 0; ni < 4; ++ni) {
                int r = wn * 64 + ni * 16 + tr;
                int c = (ko * 4 + quad) ^ (r & 7);
                bf[ni] = *(const bf16x8*)(Bs + (r * 8 + c) * 8);
            }
#pragma unroll
            for (int mi = 0; mi < 4; ++mi)
#pragma unroll
                for (int ni = 0; ni < 4; ++ni)
                    acc[mi][ni] = __builtin_amdgcn_mfma_f32_16x16x32_bf16(
                        af[mi], bf[ni], acc[mi][ni], 0, 0, 0);
        }
        __syncthreads();
    }

    // Epilogue: C/D layout col = lane&15, row = quad*4 + reg.
#pragma unroll
    for (int mi = 0; mi < 4; ++mi)
#pragma unroll
        for (int ni = 0; ni < 4; ++ni) {
            const int col = n0 + wn * 64 + ni * 16 + tr;
            const float bv = bias[col];
#pragma unroll
            for (int r = 0; r < 4; ++r) {
                const int row = m0 + wm * 64 + mi * 16 + quad * 4 + r;
                Y[(size_t)row * 1024 + col] = __float2bfloat16(acc[mi][ni][r] + bv);
            }
        }
}

// ---------------- norm: out = y / max(||y||,eps) * g * 32, 2 rows/block ----------------
__global__ __launch_bounds__(256)
void rmsnorm2(const __hip_bfloat16* __restrict__ y, const float* __restrict__ g,
              float* __restrict__ out) {
    const int wave = threadIdx.x >> 6;     // 0..3
    const int sub  = wave >> 1;            // which of 2 rows
    const int t    = threadIdx.x & 127;    // 0..127 within row
    const int row  = blockIdx.x * 2 + sub;
    const size_t base = (size_t)row * 1024 + t * 8;

    union { uint4 u; ushort s[8]; } U;
    U.u = *(const uint4*)(y + base);
    float v[8];
#pragma unroll
    for (int j = 0; j < 8; ++j)
        v[j] = __bfloat162float(*(const __hip_bfloat16*)&U.s[j]);

    float ss = 0.f;
#pragma unroll
    for (int j = 0; j < 8; ++j) ss += v[j] * v[j];
#pragma unroll
    for (int off = 32; off > 0; off >>= 1)
        ss += __shfl_down(ss, off, 64);

    __shared__ float wsum[4];
    if ((threadIdx.x & 63) == 0) wsum[wave] = ss;
    __syncthreads();
    const float total = wsum[sub * 2] + wsum[sub * 2 + 1];
    const float sc = 32.0f / fmaxf(sqrtf(total), 1e-12f);

    const float4 g0 = *(const float4*)(g + t * 8);
    const float4 g1 = *(const float4*)(g + t * 8 + 4);
    float4 o0, o1;
    o0.x = v[0] * sc * g0.x; o0.y = v[1] * sc * g0.y;
    o0.z = v[2] * sc * g0.z; o0.w = v[3] * sc * g0.w;
    o1.x = v[4] * sc * g1.x; o1.y = v[5] * sc * g1.y;
    o1.z = v[6] * sc * g1.z; o1.w = v[7] * sc * g1.w;
    *(float4*)(out + base)     = o0;
    *(float4*)(out + base + 4) = o1;
}

extern "C" void kernel_launch(void* const* d_in, const int* in_sizes, int n_in,
                              void* d_out, int out_size, void* d_ws, size_t ws_size,
                              hipStream_t stream) {
    const float* x     = (const float*)d_in[0];   // (16384, 1024)
    const float* w_qkv = (const float*)d_in[1];   // (1536, 1024)
    const float* w_out = (const float*)d_in[2];   // (1024, 512)
    const float* b_out = (const float*)d_in[3];   // (1024,)
    const float* g     = (const float*)d_in[4];   // (1, 1024)

    const int B = 16384, D = 1024, H = 512;
    const float* wv = w_qkv + (size_t)2 * H * D;  // v-rows: (512, 1024)

    char* ws = (char*)d_ws;
    size_t off = 0;
    __hip_bfloat16* weff_bf = (__hip_bfloat16*)(ws + off); off += (size_t)D * D * 2;  // 2 MB
    __hip_bfloat16* y_bf    = (__hip_bfloat16*)(ws + off); off += (size_t)B * D * 2;  // 32 MB

    weff_fused<<<dim3(D / 64, D / 64), 256, 0, stream>>>(w_out, wv, weff_bf);
    main_gemm<<<1024, 256, 0, stream>>>(x, weff_bf, b_out, y_bf);
    rmsnorm2<<<B / 2, 256, 0, stream>>>(y_bf, g, (float*)d_out);
}